// Round 18
// baseline (408.392 us; speedup 1.0000x reference)
//
#include <hip/hip_runtime.h>
#include <hip/hip_bf16.h>
#include <math.h>

#define D_IN   256
#define D_OUT  128
#define NHB    256   // coarse-sort blocks (hist + scatter replay partition)

typedef __attribute__((ext_vector_type(8))) short short8;
typedef __attribute__((ext_vector_type(4))) float floatx4;

__device__ __forceinline__ unsigned short f2bf(float f) {
  union { float f; unsigned u; } v; v.f = f;
  unsigned r = v.u + 0x7fffu + ((v.u >> 16) & 1u);  // RNE
  return (unsigned short)(r >> 16);
}

// ---------------------------------------------------------------------------
// L1: FUSED coarse-histogram + repack (512 thr) + ticket reset.
// ---------------------------------------------------------------------------
__global__ __launch_bounds__(512) void hist_prep_kernel(
    const float* __restrict__ Wl, const float* __restrict__ Wh,
    const float* __restrict__ Wm, unsigned short* __restrict__ Bpack,
    const int* __restrict__ dst, int* __restrict__ bh, int E, int NB1,
    int* __restrict__ ticket) {
  __shared__ int hist[1024];  // NB1 <= 1024 (N <= 131072)
  const int bid = blockIdx.x;
  const int t = threadIdx.x;
  if (bid == 0 && t == 0) *ticket = 0;  // reset for scan_kernel (each replay)
  if (bid < NHB) {
    for (int k = t; k < NB1; k += 512) hist[k] = 0;
    __syncthreads();
    const int chunk = (E + NHB - 1) / NHB;
    const int base = bid * chunk;
    const int lim = min(E, base + chunk);
    for (int e = base + t; e < lim; e += 512) atomicAdd(&hist[dst[e] >> 7], 1);
    __syncthreads();
    for (int k = t; k < NB1; k += 512) bh[k * NHB + bid] = hist[k];
  } else {
    // repack: frag f = kt*24+nt holds B[k=kt*32+quad*8+j][n=nt*16+(lane&15)]
    int tt = (bid - NHB) * 512 + t;  // 0..98303
    int j = tt & 7;
    int lane = (tt >> 3) & 63;
    int f = tt >> 9;  // 0..191
    int nt = f % 24, kt = f / 24;
    int k = kt * 32 + (lane >> 4) * 8 + j;
    int n_ = nt * 16 + (lane & 15);
    const float* W = (n_ < 128) ? Wl : (n_ < 256 ? Wh : Wm);
    Bpack[tt] = f2bf(W[k * D_OUT + (n_ & 127)]);
  }
}

// ---------------------------------------------------------------------------
// L2: SINGLE-PASS scan (scan1 + last-block scan2 via device ticket).
// Consumers read bhscan[i] + bsum[i>>11].
// ---------------------------------------------------------------------------
__global__ __launch_bounds__(512) void scan_kernel(
    const int* __restrict__ bh, int* __restrict__ bhscan,
    int* __restrict__ bsum, int M, int nscan, int* __restrict__ ticket) {
  __shared__ int sd[512];
  __shared__ int lastFlag;
  const int sb = blockIdx.x;
  const int t = threadIdx.x;
  int base = sb * 2048 + t * 4;
  int v0 = base + 0 < M ? bh[base + 0] : 0;
  int v1 = base + 1 < M ? bh[base + 1] : 0;
  int v2 = base + 2 < M ? bh[base + 2] : 0;
  int v3 = base + 3 < M ? bh[base + 3] : 0;
  int tsum = v0 + v1 + v2 + v3;
  sd[t] = tsum;
  __syncthreads();
  for (int off = 1; off < 512; off <<= 1) {
    int add = (t >= off) ? sd[t - off] : 0;
    __syncthreads();
    sd[t] += add;
    __syncthreads();
  }
  int excl = sd[t] - tsum;
  if (base + 0 < M) bhscan[base + 0] = excl;
  if (base + 1 < M) bhscan[base + 1] = excl + v0;
  if (base + 2 < M) bhscan[base + 2] = excl + v0 + v1;
  if (base + 3 < M) bhscan[base + 3] = excl + v0 + v1 + v2;
  if (t == 511) {
    bsum[sb] = sd[511];
    __threadfence();  // release: bsum visible before ticket bump
    int prev = atomicAdd(ticket, 1);
    lastFlag = (prev == nscan - 1);
  }
  __syncthreads();
  if (!lastFlag) return;
  __threadfence();  // acquire: see all other blocks' bsum
  int v = t < nscan ? bsum[t] : 0;
  sd[t] = v;
  __syncthreads();
  for (int off = 1; off < 512; off <<= 1) {
    int add = (t >= off) ? sd[t - off] : 0;
    __syncthreads();
    sd[t] += add;
    __syncthreads();
  }
  if (t < nscan) bsum[t] = sd[t] - v;  // exclusive
}

// ---------------------------------------------------------------------------
// gemm tile as a device function — hosted by L3/L4. Identical math to r16:
// LDS-staged A with fused f32->bf16 cvt (RNE), XOR-swizzled chunks, bf16
// MFMA K-loop, two-pass LDS epilogue -> Zg (512B rows) + Zm plane.
// ---------------------------------------------------------------------------
#define LDSROW 392  // shorts/row for the epilogue tile: 784 B (16B-aligned)
__device__ __forceinline__ void gemm_tile(
    int gemm_id, unsigned short* lds, const float* __restrict__ x,
    const unsigned short* __restrict__ Bpack, unsigned short* __restrict__ Zg,
    unsigned short* __restrict__ Zm, int n_nodes) {
  const int lane = threadIdx.x & 63;
  const int w = threadIdx.x >> 6;  // 0..7: column group (3 ctiles)
  const int rowbase = gemm_id * 64;
  const int m16 = lane & 15, quad = lane >> 4;

  // cooperative A staging with fused f32->bf16: 64 rows x 256 floats.
  {
    const float4* xf = (const float4*)x;  // 64 float4 per row
#pragma unroll
    for (int i = 0; i < 4; i++) {
      int idx = i * 512 + threadIdx.x;  // 0..2047
      int row = idx >> 5, c = idx & 31;
      int gr = rowbase + row;
      if (gr > n_nodes - 1) gr = n_nodes - 1;  // clamp; stores are guarded
      float4 f0 = xf[(size_t)gr * 64 + c * 2];
      float4 f1 = xf[(size_t)gr * 64 + c * 2 + 1];
      unsigned w0, w1, w2, w3;
      asm("v_cvt_pk_bf16_f32 %0, %1, %2" : "=v"(w0) : "v"(f0.x), "v"(f0.y));
      asm("v_cvt_pk_bf16_f32 %0, %1, %2" : "=v"(w1) : "v"(f0.z), "v"(f0.w));
      asm("v_cvt_pk_bf16_f32 %0, %1, %2" : "=v"(w2) : "v"(f1.x), "v"(f1.y));
      asm("v_cvt_pk_bf16_f32 %0, %1, %2" : "=v"(w3) : "v"(f1.z), "v"(f1.w));
      union { uint4 u; short8 s8; } cv;
      cv.u = make_uint4(w0, w1, w2, w3);
      int pc = (c & ~7) | ((c ^ row) & 7);
      ((short8*)lds)[row * 32 + pc] = cv.s8;
    }
  }
  __syncthreads();

  floatx4 acc[4][3];
#pragma unroll
  for (int s = 0; s < 4; s++)
#pragma unroll
    for (int c = 0; c < 3; c++) acc[s][c] = (floatx4)(0.f);

  const short8* bp = (const short8*)Bpack + lane;

#pragma unroll
  for (int kt = 0; kt < 8; kt++) {
    short8 a[4];
#pragma unroll
    for (int s = 0; s < 4; s++) {
      int r_ = s * 16 + m16;
      int c_ = kt * 4 + quad;
      int pc = (c_ & ~7) | ((c_ ^ r_) & 7);
      a[s] = ((const short8*)lds)[r_ * 32 + pc];
    }
#pragma unroll
    for (int c = 0; c < 3; c++) {
      short8 b = bp[(kt * 24 + w * 3 + c) * 64];
#pragma unroll
      for (int s = 0; s < 4; s++)
        acc[s][c] =
            __builtin_amdgcn_mfma_f32_16x16x32_bf16(a[s], b, acc[s][c], 0, 0, 0);
    }
  }

  __syncthreads();  // all A-tile reads done before epilogue overwrites lds
  unsigned short* tile = lds;

#pragma unroll
  for (int half = 0; half < 2; half++) {
    if (half) __syncthreads();
#pragma unroll
    for (int s = 0; s < 2; s++)
#pragma unroll
      for (int c = 0; c < 3; c++)
#pragma unroll
        for (int r = 0; r < 4; r++)
          tile[(s * 16 + quad * 4 + r) * LDSROW + (w * 3 + c) * 16 + m16] =
              f2bf(acc[half * 2 + s][c][r]);
    __syncthreads();
#pragma unroll
    for (int it = 0; it < 3; it++) {
      int chunk = it * 512 + threadIdx.x;
      int row = chunk / 48, c8 = chunk % 48;
      int grow = rowbase + half * 32 + row;
      if (grow < n_nodes) {
        short8 v = *(const short8*)&tile[row * LDSROW + c8 * 8];
        if (c8 < 32)
          *(short8*)(Zg + (size_t)grow * 256 + c8 * 8) = v;
        else
          *(short8*)(Zm + (size_t)grow * 128 + (c8 - 32) * 8) = v;
      }
    }
  }
}

// ---------------------------------------------------------------------------
// L3: coarse scatter (NHB blocks) + gemmA tiles (chunky 2-way split so this
// composite becomes VISIBLE in the top-5 — decomposition probe).
// ---------------------------------------------------------------------------
__global__ __launch_bounds__(512, 4) void scatter_gemm_kernel(
    const int* __restrict__ src, const int* __restrict__ dst,
    const float* __restrict__ wlo, const float* __restrict__ whi,
    const int* __restrict__ bhscan, const int* __restrict__ bsum,
    uint2* __restrict__ tmp, int E, int NB1, int ngA,
    const float* __restrict__ x, const unsigned short* __restrict__ Bpack,
    unsigned short* __restrict__ Zg, unsigned short* __restrict__ Zm,
    int n_nodes) {
  __shared__ unsigned short lds[16384];
  const int bid = blockIdx.x;
  const int mn = min(NHB, ngA), m2 = 2 * mn;
  int role, idx;
  if (bid < m2) {
    role = bid & 1;  // 0 = scatter, 1 = gemm
    idx = bid >> 1;
  } else if (NHB < ngA) {
    role = 1;
    idx = bid - m2 + mn;
  } else {
    role = 0;
    idx = bid - m2 + mn;
  }
  if (role == 0) {
    int rb = idx;
    int* cur = (int*)lds;
    int t = threadIdx.x;
    for (int k = t; k < NB1; k += 512) {
      int i2 = k * NHB + rb;
      cur[k] = bhscan[i2] + bsum[i2 >> 11];
    }
    __syncthreads();
    const int chunk = (E + NHB - 1) / NHB;
    const int base = rb * chunk;
    const int lim = min(E, base + chunk);
    for (int e = base + t; e < lim; e += 512) {
      int d = dst[e];
      int pos = atomicAdd(&cur[d >> 7], 1);  // LDS atomic
      unsigned wl = f2bf(wlo[e]), wh = f2bf(whi[e]);
      tmp[pos] = make_uint2((unsigned)src[e] | ((unsigned)(d & 127) << 20),
                            wl | (wh << 16));
    }
  } else {
    gemm_tile(idx, lds, x, Bpack, Zg, Zm, n_nodes);  // tiles 0..ngA-1
  }
}

// ---------------------------------------------------------------------------
// L4: fine sort (NB1 blocks) + gemmB tiles (rest). Fine finally gets
// overlap cover; composite visible in top-5.
// ---------------------------------------------------------------------------
__global__ __launch_bounds__(512, 4) void fine_gemm_kernel(
    const uint2* __restrict__ tmp, const int* __restrict__ bhscan,
    const int* __restrict__ bsum, uint2* __restrict__ meta,
    int* __restrict__ rowptr, int NB1, int n, int E, int ngB, int gbase,
    const float* __restrict__ x, const unsigned short* __restrict__ Bpack,
    unsigned short* __restrict__ Zg, unsigned short* __restrict__ Zm,
    int n_nodes) {
  __shared__ unsigned short lds[16384];
  const int bid = blockIdx.x;
  const int mn = min(NB1, ngB), m2 = 2 * mn;
  int role, idx;
  if (bid < m2) {
    role = bid & 1;  // 0 = fine, 1 = gemm
    idx = bid >> 1;
  } else if (NB1 < ngB) {
    role = 1;
    idx = bid - m2 + mn;
  } else {
    role = 0;
    idx = bid - m2 + mn;
  }
  if (role == 1) {
    gemm_tile(gbase + idx, lds, x, Bpack, Zg, Zm, n_nodes);
    return;
  }
  const int b = idx;
  int* fh = (int*)lds;
  int* sd = fh + 128;
  int* cur = fh + 256;
  const int t = threadIdx.x;
  auto scanidx = [&](int i) { return bhscan[i] + bsum[i >> 11]; };
  const int s0 = scanidx(b * NHB);
  const int s1 = (b == NB1 - 1) ? E : scanidx((b + 1) * NHB);

  if (t < 128) fh[t] = 0;
  __syncthreads();
  for (int i = s0 + t; i < s1; i += 512)
    atomicAdd(&fh[(tmp[i].x >> 20) & 127], 1);
  __syncthreads();

  if (t < 128) sd[t] = fh[t];
  __syncthreads();
  for (int off = 1; off < 128; off <<= 1) {
    int add = (t >= off && t < 128) ? sd[t - off] : 0;
    __syncthreads();
    if (t < 128) sd[t] += add;
    __syncthreads();
  }
  if (t < 128) {
    int excl = sd[t] - fh[t];
    cur[t] = excl;
    int node = b * 128 + t;
    if (node < n) rowptr[node] = s0 + excl;
  }
  if (b == 0 && t == 0) rowptr[n] = E;
  __syncthreads();

  for (int i = s0 + t; i < s1; i += 512) {
    uint2 v = tmp[i];
    int d = (v.x >> 20) & 127;
    int pos = s0 + atomicAdd(&cur[d], 1);  // LDS atomic
    meta[pos] = make_uint2(v.x & 0xFFFFFu, v.y);
  }
}

// ---------------------------------------------------------------------------
// L5: K_node — r16 simple loop restored (r17's deeper pipeline confirmed
// neutral-to-negative; ~118us is node's floor across 6 variants).
// ---------------------------------------------------------------------------
__global__ __launch_bounds__(128) void node_kernel(
    const unsigned short* __restrict__ Zg, const unsigned short* __restrict__ Zm,
    const int* __restrict__ rowptr, const unsigned long long* __restrict__ meta,
    const float* __restrict__ a_low, const float* __restrict__ a_high,
    const float* __restrict__ a_mlp, const float* __restrict__ att_vec,
    float* __restrict__ out, int n_nodes) {
  int node = blockIdx.x * 2 + (threadIdx.x >> 6);
  if (node >= n_nodes) return;
  node = __builtin_amdgcn_readfirstlane(node);  // wave-uniform -> s_loads
  const int lane = threadIdx.x & 63;
  const int isHigh = lane >> 5;
  const int dbase = (lane & 31) * 4;
  const char* Zb = (const char*)Zg;

  const int start = rowptr[node];
  const int end = rowptr[node + 1];

  float acc0 = 0.f, acc1 = 0.f, acc2 = 0.f, acc3 = 0.f;
  auto wsel = [&](unsigned p) {
    return __uint_as_float(isHigh ? (p & 0xffff0000u) : (p << 16));
  };
  auto step = [&](uint2 z, float wv) {
    acc0 += wv * __uint_as_float(z.x << 16);
    acc1 += wv * __uint_as_float(z.x & 0xffff0000u);
    acc2 += wv * __uint_as_float(z.y << 16);
    acc3 += wv * __uint_as_float(z.y & 0xffff0000u);
  };

  int j = start;
  const int nfull = (end - start) & ~7;
  for (; j < start + nfull; j += 8) {
    unsigned long long m[8];
    uint2 z[8];
#pragma unroll
    for (int u = 0; u < 8; u++) m[u] = __builtin_nontemporal_load(&meta[j + u]);
#pragma unroll
    for (int u = 0; u < 8; u++)
      z[u] = *(const uint2*)(Zb + ((size_t)(unsigned)m[u]) * 512 + lane * 8);
#pragma unroll
    for (int u = 0; u < 8; u++) step(z[u], wsel((unsigned)(m[u] >> 32)));
  }
  for (; j < end; j++) {
    unsigned long long m0 = __builtin_nontemporal_load(&meta[j]);
    uint2 z0 = *(const uint2*)(Zb + ((size_t)(unsigned)m0) * 512 + lane * 8);
    step(z0, wsel((unsigned)(m0 >> 32)));
  }

  float h0 = fmaxf(acc0, 0.f), h1 = fmaxf(acc1, 0.f);
  float h2 = fmaxf(acc2, 0.f), h3 = fmaxf(acc3, 0.f);

  unsigned long long zmq = __builtin_nontemporal_load(
      (const unsigned long long*)((const char*)Zm + (size_t)node * 256 +
                                  (size_t)(lane & 31) * 8));
  unsigned zmx = (unsigned)zmq, zmy = (unsigned)(zmq >> 32);
  float q0 = fmaxf(__uint_as_float(zmx << 16), 0.f);
  float q1 = fmaxf(__uint_as_float(zmx & 0xffff0000u), 0.f);
  float q2 = fmaxf(__uint_as_float(zmy << 16), 0.f);
  float q3 = fmaxf(__uint_as_float(zmy & 0xffff0000u), 0.f);

  const float* av_b = isHigh ? a_high : a_low;
  float4 ab = *(const float4*)&av_b[dbase];
  float4 am = *(const float4*)&a_mlp[dbase];
  float v1 = h0 * ab.x + h1 * ab.y + h2 * ab.z + h3 * ab.w;
  float v2 = isHigh ? 0.f : (q0 * am.x + q1 * am.y + q2 * am.z + q3 * am.w);
#pragma unroll
  for (int off = 1; off < 32; off <<= 1) {
    v1 += __shfl_xor(v1, off);
    v2 += __shfl_xor(v2, off);
  }
  float s_lo = __shfl(v1, 0);
  float s_hi = __shfl(v1, 32);
  float s_ml = __shfl(v2, 0);

  float g0 = 1.f / (1.f + __expf(-s_lo));
  float g1 = 1.f / (1.f + __expf(-s_hi));
  float g2 = 1.f / (1.f + __expf(-s_ml));
  const float inv3 = 1.f / 3.f;
  float m0 = (g0 * att_vec[0] + g1 * att_vec[3] + g2 * att_vec[6]) * inv3;
  float m1 = (g0 * att_vec[1] + g1 * att_vec[4] + g2 * att_vec[7]) * inv3;
  float m2 = (g0 * att_vec[2] + g1 * att_vec[5] + g2 * att_vec[8]) * inv3;
  float mx = fmaxf(m0, fmaxf(m1, m2));
  float e0 = __expf(m0 - mx), e1 = __expf(m1 - mx), e2 = __expf(m2 - mx);
  float inv = 1.f / (e0 + e1 + e2);
  float c0 = 3.f * inv * e0, c1 = 3.f * inv * e1, c2 = 3.f * inv * e2;

  float hh0 = __shfl_xor(h0, 32);
  float hh1 = __shfl_xor(h1, 32);
  float hh2 = __shfl_xor(h2, 32);
  float hh3 = __shfl_xor(h3, 32);

  if (!isHigh) {
    floatx4 o;
    o.x = c0 * h0 + c1 * hh0 + c2 * q0;
    o.y = c0 * h1 + c1 * hh1 + c2 * q1;
    o.z = c0 * h2 + c1 * hh2 + c2 * q2;
    o.w = c0 * h3 + c1 * hh3 + c2 * q3;
    __builtin_nontemporal_store(o,
                                (floatx4*)&out[(size_t)node * D_OUT + dbase]);
  }
}

// ---------------------------------------------------------------------------
extern "C" void kernel_launch(void* const* d_in, const int* in_sizes, int n_in,
                              void* d_out, int out_size, void* d_ws,
                              size_t ws_size, hipStream_t stream) {
  const float* x    = (const float*)d_in[0];
  const int*   esrc = (const int*)d_in[1];
  const int*   edst = (const int*)d_in[2];
  const float* wlo  = (const float*)d_in[3];
  const float* whi  = (const float*)d_in[4];
  const float* Wl   = (const float*)d_in[6];
  const float* Wh   = (const float*)d_in[7];
  const float* Wm   = (const float*)d_in[8];
  const float* alo  = (const float*)d_in[9];
  const float* ahi  = (const float*)d_in[10];
  const float* amlp = (const float*)d_in[11];
  const float* av   = (const float*)d_in[12];
  float* out = (float*)d_out;

  const int N = in_sizes[0] / D_IN;  // 100000
  const int E = in_sizes[1];         // 1600000
  const int NB1 = (N + 127) >> 7;    // coarse buckets (782)
  const int M = NB1 * NHB;           // bh entries (200192)

  char* ws = (char*)d_ws;
  size_t off = 0;
  auto carve = [&](size_t bytes) -> void* {
    void* p = ws + off;
    off = (off + bytes + 255) & ~(size_t)255;
    return p;
  };
  unsigned short* Zg     = (unsigned short*)carve((size_t)N * 256 * 2);
  unsigned short* Zm     = (unsigned short*)carve((size_t)N * 128 * 2);
  unsigned short* Bpack  = (unsigned short*)carve(98304 * 2);
  int*   bh     = (int*)carve((size_t)M * 4);
  int*   bhscan = (int*)carve((size_t)M * 4);
  int*   bsum   = (int*)carve(512 * 4);
  int*   rowptr = (int*)carve((size_t)(N + 1) * 4);
  int*   ticket = (int*)carve(256);
  uint2* tmp    = (uint2*)carve((size_t)E * 8);
  uint2* meta   = (uint2*)carve((size_t)E * 8);

  int nscan = (M + 2047) / 2048;  // 98
  int ngemm = (N + 63) / 64;      // 1563
  int NGA = 1000;                 // tiles hosted by L3
  int NGB = ngemm - NGA;          // 563 tiles hosted by L4

  // L1: hist + repack (+ ticket reset)
  hist_prep_kernel<<<NHB + 192, 512, 0, stream>>>(Wl, Wh, Wm, Bpack, edst, bh,
                                                  E, NB1, ticket);
  // L2: single-pass scan
  scan_kernel<<<nscan, 512, 0, stream>>>(bh, bhscan, bsum, M, nscan, ticket);
  // L3: scatter + gemmA (visible composite)
  scatter_gemm_kernel<<<NHB + NGA, 512, 0, stream>>>(
      esrc, edst, wlo, whi, bhscan, bsum, tmp, E, NB1, NGA, x, Bpack, Zg, Zm,
      N);
  // L4: fine + gemmB (visible composite)
  fine_gemm_kernel<<<NB1 + NGB, 512, 0, stream>>>(
      tmp, bhscan, bsum, meta, rowptr, NB1, N, E, NGB, NGA, x, Bpack, Zg, Zm,
      N);
  // L5: node
  node_kernel<<<(N + 1) / 2, 128, 0, stream>>>(
      Zg, Zm, rowptr, (const unsigned long long*)meta, alo, ahi, amlp, av, out,
      N);
}

// Round 19
// 394.668 us; speedup vs baseline: 1.0348x; 1.0348x over previous
//
#include <hip/hip_runtime.h>
#include <hip/hip_bf16.h>
#include <math.h>

#define D_IN   256
#define D_OUT  128
#define NHB    256   // coarse-sort blocks (hist + scatter replay partition)

typedef __attribute__((ext_vector_type(8))) short short8;
typedef __attribute__((ext_vector_type(4))) float floatx4;

__device__ __forceinline__ unsigned short f2bf(float f) {
  union { float f; unsigned u; } v; v.f = f;
  unsigned r = v.u + 0x7fffu + ((v.u >> 16) & 1u);  // RNE
  return (unsigned short)(r >> 16);
}

// ---------------------------------------------------------------------------
// L1: FUSED coarse-histogram + repack (512 thr) + ticket reset.
// ---------------------------------------------------------------------------
__global__ __launch_bounds__(512) void hist_prep_kernel(
    const float* __restrict__ Wl, const float* __restrict__ Wh,
    const float* __restrict__ Wm, unsigned short* __restrict__ Bpack,
    const int* __restrict__ dst, int* __restrict__ bh, int E, int NB1,
    int* __restrict__ ticket) {
  __shared__ int hist[1024];  // NB1 <= 1024 (N <= 131072)
  const int bid = blockIdx.x;
  const int t = threadIdx.x;
  if (bid == 0 && t == 0) *ticket = 0;  // reset for scan_kernel (each replay)
  if (bid < NHB) {
    for (int k = t; k < NB1; k += 512) hist[k] = 0;
    __syncthreads();
    const int chunk = (E + NHB - 1) / NHB;
    const int base = bid * chunk;
    const int lim = min(E, base + chunk);
    for (int e = base + t; e < lim; e += 512) atomicAdd(&hist[dst[e] >> 7], 1);
    __syncthreads();
    for (int k = t; k < NB1; k += 512) bh[k * NHB + bid] = hist[k];
  } else {
    // repack: frag f = kt*24+nt holds B[k=kt*32+quad*8+j][n=nt*16+(lane&15)]
    int tt = (bid - NHB) * 512 + t;  // 0..98303
    int j = tt & 7;
    int lane = (tt >> 3) & 63;
    int f = tt >> 9;  // 0..191
    int nt = f % 24, kt = f / 24;
    int k = kt * 32 + (lane >> 4) * 8 + j;
    int n_ = nt * 16 + (lane & 15);
    const float* W = (n_ < 128) ? Wl : (n_ < 256 ? Wh : Wm);
    Bpack[tt] = f2bf(W[k * D_OUT + (n_ & 127)]);
  }
}

// ---------------------------------------------------------------------------
// L2: SINGLE-PASS scan (scan1 + last-block scan2 via device ticket).
// Consumers read bhscan[i] + bsum[i>>11].
// ---------------------------------------------------------------------------
__global__ __launch_bounds__(512) void scan_kernel(
    const int* __restrict__ bh, int* __restrict__ bhscan,
    int* __restrict__ bsum, int M, int nscan, int* __restrict__ ticket) {
  __shared__ int sd[512];
  __shared__ int lastFlag;
  const int sb = blockIdx.x;
  const int t = threadIdx.x;
  int base = sb * 2048 + t * 4;
  int v0 = base + 0 < M ? bh[base + 0] : 0;
  int v1 = base + 1 < M ? bh[base + 1] : 0;
  int v2 = base + 2 < M ? bh[base + 2] : 0;
  int v3 = base + 3 < M ? bh[base + 3] : 0;
  int tsum = v0 + v1 + v2 + v3;
  sd[t] = tsum;
  __syncthreads();
  for (int off = 1; off < 512; off <<= 1) {
    int add = (t >= off) ? sd[t - off] : 0;
    __syncthreads();
    sd[t] += add;
    __syncthreads();
  }
  int excl = sd[t] - tsum;
  if (base + 0 < M) bhscan[base + 0] = excl;
  if (base + 1 < M) bhscan[base + 1] = excl + v0;
  if (base + 2 < M) bhscan[base + 2] = excl + v0 + v1;
  if (base + 3 < M) bhscan[base + 3] = excl + v0 + v1 + v2;
  if (t == 511) {
    bsum[sb] = sd[511];
    __threadfence();  // release: bsum visible before ticket bump
    int prev = atomicAdd(ticket, 1);
    lastFlag = (prev == nscan - 1);
  }
  __syncthreads();
  if (!lastFlag) return;
  __threadfence();  // acquire: see all other blocks' bsum
  int v = t < nscan ? bsum[t] : 0;
  sd[t] = v;
  __syncthreads();
  for (int off = 1; off < 512; off <<= 1) {
    int add = (t >= off) ? sd[t - off] : 0;
    __syncthreads();
    sd[t] += add;
    __syncthreads();
  }
  if (t < nscan) bsum[t] = sd[t] - v;  // exclusive
}

// ---------------------------------------------------------------------------
// L3: FUSED gemm + coarse scatter (proven monolithic form — the single
// role-split that pays; r15/r18 proved slicing gemm thinner regresses).
// ---------------------------------------------------------------------------
#define LDSROW 392  // shorts/row for the epilogue tile: 784 B (16B-aligned)
__global__ __launch_bounds__(512, 4) void gemm_sort_kernel(
    const float* __restrict__ x,
    const unsigned short* __restrict__ Bpack, unsigned short* __restrict__ Zg,
    unsigned short* __restrict__ Zm, int n_nodes, const int* __restrict__ src,
    const int* __restrict__ dst, const float* __restrict__ wlo,
    const float* __restrict__ whi, const int* __restrict__ bhscan,
    const int* __restrict__ bsum, uint2* __restrict__ tmp, int E, int NB1) {
  __shared__ unsigned short lds[16384];  // 32 KB: A-tile, then epilogue tile
  const int bid = blockIdx.x;

  int gemm_id;
  if (bid < 2 * NHB) {
    if ((bid & 1) == 0) {  // ---- coarse scatter block ----
      int rb = bid >> 1;
      int* cur = (int*)lds;
      int t = threadIdx.x;
      for (int k = t; k < NB1; k += 512) {
        int idx = k * NHB + rb;
        cur[k] = bhscan[idx] + bsum[idx >> 11];
      }
      __syncthreads();
      const int chunk = (E + NHB - 1) / NHB;
      const int base = rb * chunk;
      const int lim = min(E, base + chunk);
      for (int e = base + t; e < lim; e += 512) {
        int d = dst[e];
        int pos = atomicAdd(&cur[d >> 7], 1);  // LDS atomic
        unsigned wl = f2bf(wlo[e]), wh = f2bf(whi[e]);
        tmp[pos] = make_uint2((unsigned)src[e] | ((unsigned)(d & 127) << 20),
                              wl | (wh << 16));
      }
      return;
    }
    gemm_id = bid >> 1;
  } else {
    gemm_id = bid - 2 * NHB + NHB;
  }

  // ---- gemm block ----
  const int lane = threadIdx.x & 63;
  const int w = threadIdx.x >> 6;  // 0..7: column group (3 ctiles)
  const int rowbase = gemm_id * 64;
  const int m16 = lane & 15, quad = lane >> 4;

  // cooperative A staging with fused f32->bf16: 64 rows x 256 floats.
  {
    const float4* xf = (const float4*)x;  // 64 float4 per row
#pragma unroll
    for (int i = 0; i < 4; i++) {
      int idx = i * 512 + threadIdx.x;  // 0..2047
      int row = idx >> 5, c = idx & 31;
      int gr = rowbase + row;
      if (gr > n_nodes - 1) gr = n_nodes - 1;  // clamp; stores are guarded
      float4 f0 = xf[(size_t)gr * 64 + c * 2];
      float4 f1 = xf[(size_t)gr * 64 + c * 2 + 1];
      unsigned w0, w1, w2, w3;
      asm("v_cvt_pk_bf16_f32 %0, %1, %2" : "=v"(w0) : "v"(f0.x), "v"(f0.y));
      asm("v_cvt_pk_bf16_f32 %0, %1, %2" : "=v"(w1) : "v"(f0.z), "v"(f0.w));
      asm("v_cvt_pk_bf16_f32 %0, %1, %2" : "=v"(w2) : "v"(f1.x), "v"(f1.y));
      asm("v_cvt_pk_bf16_f32 %0, %1, %2" : "=v"(w3) : "v"(f1.z), "v"(f1.w));
      union { uint4 u; short8 s8; } cv;
      cv.u = make_uint4(w0, w1, w2, w3);
      int pc = (c & ~7) | ((c ^ row) & 7);
      ((short8*)lds)[row * 32 + pc] = cv.s8;
    }
  }
  __syncthreads();

  floatx4 acc[4][3];
#pragma unroll
  for (int s = 0; s < 4; s++)
#pragma unroll
    for (int c = 0; c < 3; c++) acc[s][c] = (floatx4)(0.f);

  const short8* bp = (const short8*)Bpack + lane;

#pragma unroll
  for (int kt = 0; kt < 8; kt++) {
    short8 a[4];
#pragma unroll
    for (int s = 0; s < 4; s++) {
      int r_ = s * 16 + m16;
      int c_ = kt * 4 + quad;
      int pc = (c_ & ~7) | ((c_ ^ r_) & 7);
      a[s] = ((const short8*)lds)[r_ * 32 + pc];
    }
#pragma unroll
    for (int c = 0; c < 3; c++) {
      short8 b = bp[(kt * 24 + w * 3 + c) * 64];
#pragma unroll
      for (int s = 0; s < 4; s++)
        acc[s][c] =
            __builtin_amdgcn_mfma_f32_16x16x32_bf16(a[s], b, acc[s][c], 0, 0, 0);
    }
  }

  __syncthreads();  // all A-tile reads done before epilogue overwrites lds
  unsigned short* tile = lds;

#pragma unroll
  for (int half = 0; half < 2; half++) {
    if (half) __syncthreads();
#pragma unroll
    for (int s = 0; s < 2; s++)
#pragma unroll
      for (int c = 0; c < 3; c++)
#pragma unroll
        for (int r = 0; r < 4; r++)
          tile[(s * 16 + quad * 4 + r) * LDSROW + (w * 3 + c) * 16 + m16] =
              f2bf(acc[half * 2 + s][c][r]);
    __syncthreads();
#pragma unroll
    for (int it = 0; it < 3; it++) {
      int chunk = it * 512 + threadIdx.x;
      int row = chunk / 48, c8 = chunk % 48;
      int grow = rowbase + half * 32 + row;
      if (grow < n_nodes) {
        short8 v = *(const short8*)&tile[row * LDSROW + c8 * 8];
        if (c8 < 32)
          *(short8*)(Zg + (size_t)grow * 256 + c8 * 8) = v;
        else
          *(short8*)(Zm + (size_t)grow * 128 + (c8 - 32) * 8) = v;
      }
    }
  }
}

// ---------------------------------------------------------------------------
// L4: fine pass (512 thr): LDS 128-bin hist + scan -> meta + rowptr.
// ---------------------------------------------------------------------------
__global__ __launch_bounds__(512) void fine_kernel(
    const uint2* __restrict__ tmp, const int* __restrict__ bhscan,
    const int* __restrict__ bsum, uint2* __restrict__ meta,
    int* __restrict__ rowptr, int NB1, int n, int E) {
  __shared__ int fh[128];
  __shared__ int sd[128];
  __shared__ int cur[128];
  const int b = blockIdx.x;
  const int t = threadIdx.x;
  auto scanidx = [&](int i) { return bhscan[i] + bsum[i >> 11]; };
  const int s0 = scanidx(b * NHB);
  const int s1 = (b == NB1 - 1) ? E : scanidx((b + 1) * NHB);

  if (t < 128) fh[t] = 0;
  __syncthreads();
  for (int i = s0 + t; i < s1; i += 512)
    atomicAdd(&fh[(tmp[i].x >> 20) & 127], 1);
  __syncthreads();

  if (t < 128) sd[t] = fh[t];
  __syncthreads();
  for (int off = 1; off < 128; off <<= 1) {
    int add = (t >= off && t < 128) ? sd[t - off] : 0;
    __syncthreads();
    if (t < 128) sd[t] += add;
    __syncthreads();
  }
  if (t < 128) {
    int excl = sd[t] - fh[t];
    cur[t] = excl;
    int node = b * 128 + t;
    if (node < n) rowptr[node] = s0 + excl;
  }
  if (b == 0 && t == 0) rowptr[n] = E;
  __syncthreads();

  for (int i = s0 + t; i < s1; i += 512) {
    uint2 v = tmp[i];
    int d = (v.x >> 20) & 127;
    int pos = s0 + atomicAdd(&cur[d], 1);  // LDS atomic
    meta[pos] = make_uint2(v.x & 0xFFFFFu, v.y);
  }
}

// ---------------------------------------------------------------------------
// L5: K_node — simple unroll-x8 loop (floor: ~118us, 400MB FETCH, proven
// across six gather variants incl. deeper pipelines / wider loads).
// ---------------------------------------------------------------------------
__global__ __launch_bounds__(128) void node_kernel(
    const unsigned short* __restrict__ Zg, const unsigned short* __restrict__ Zm,
    const int* __restrict__ rowptr, const unsigned long long* __restrict__ meta,
    const float* __restrict__ a_low, const float* __restrict__ a_high,
    const float* __restrict__ a_mlp, const float* __restrict__ att_vec,
    float* __restrict__ out, int n_nodes) {
  int node = blockIdx.x * 2 + (threadIdx.x >> 6);
  if (node >= n_nodes) return;
  node = __builtin_amdgcn_readfirstlane(node);  // wave-uniform -> s_loads
  const int lane = threadIdx.x & 63;
  const int isHigh = lane >> 5;
  const int dbase = (lane & 31) * 4;
  const char* Zb = (const char*)Zg;

  const int start = rowptr[node];
  const int end = rowptr[node + 1];

  float acc0 = 0.f, acc1 = 0.f, acc2 = 0.f, acc3 = 0.f;
  auto wsel = [&](unsigned p) {
    return __uint_as_float(isHigh ? (p & 0xffff0000u) : (p << 16));
  };
  auto step = [&](uint2 z, float wv) {
    acc0 += wv * __uint_as_float(z.x << 16);
    acc1 += wv * __uint_as_float(z.x & 0xffff0000u);
    acc2 += wv * __uint_as_float(z.y << 16);
    acc3 += wv * __uint_as_float(z.y & 0xffff0000u);
  };

  int j = start;
  const int nfull = (end - start) & ~7;
  for (; j < start + nfull; j += 8) {
    unsigned long long m[8];
    uint2 z[8];
#pragma unroll
    for (int u = 0; u < 8; u++) m[u] = __builtin_nontemporal_load(&meta[j + u]);
#pragma unroll
    for (int u = 0; u < 8; u++)
      z[u] = *(const uint2*)(Zb + ((size_t)(unsigned)m[u]) * 512 + lane * 8);
#pragma unroll
    for (int u = 0; u < 8; u++) step(z[u], wsel((unsigned)(m[u] >> 32)));
  }
  for (; j < end; j++) {
    unsigned long long m0 = __builtin_nontemporal_load(&meta[j]);
    uint2 z0 = *(const uint2*)(Zb + ((size_t)(unsigned)m0) * 512 + lane * 8);
    step(z0, wsel((unsigned)(m0 >> 32)));
  }

  float h0 = fmaxf(acc0, 0.f), h1 = fmaxf(acc1, 0.f);
  float h2 = fmaxf(acc2, 0.f), h3 = fmaxf(acc3, 0.f);

  unsigned long long zmq = __builtin_nontemporal_load(
      (const unsigned long long*)((const char*)Zm + (size_t)node * 256 +
                                  (size_t)(lane & 31) * 8));
  unsigned zmx = (unsigned)zmq, zmy = (unsigned)(zmq >> 32);
  float q0 = fmaxf(__uint_as_float(zmx << 16), 0.f);
  float q1 = fmaxf(__uint_as_float(zmx & 0xffff0000u), 0.f);
  float q2 = fmaxf(__uint_as_float(zmy << 16), 0.f);
  float q3 = fmaxf(__uint_as_float(zmy & 0xffff0000u), 0.f);

  const float* av_b = isHigh ? a_high : a_low;
  float4 ab = *(const float4*)&av_b[dbase];
  float4 am = *(const float4*)&a_mlp[dbase];
  float v1 = h0 * ab.x + h1 * ab.y + h2 * ab.z + h3 * ab.w;
  float v2 = isHigh ? 0.f : (q0 * am.x + q1 * am.y + q2 * am.z + q3 * am.w);
#pragma unroll
  for (int off = 1; off < 32; off <<= 1) {
    v1 += __shfl_xor(v1, off);
    v2 += __shfl_xor(v2, off);
  }
  float s_lo = __shfl(v1, 0);
  float s_hi = __shfl(v1, 32);
  float s_ml = __shfl(v2, 0);

  float g0 = 1.f / (1.f + __expf(-s_lo));
  float g1 = 1.f / (1.f + __expf(-s_hi));
  float g2 = 1.f / (1.f + __expf(-s_ml));
  const float inv3 = 1.f / 3.f;
  float m0 = (g0 * att_vec[0] + g1 * att_vec[3] + g2 * att_vec[6]) * inv3;
  float m1 = (g0 * att_vec[1] + g1 * att_vec[4] + g2 * att_vec[7]) * inv3;
  float m2 = (g0 * att_vec[2] + g1 * att_vec[5] + g2 * att_vec[8]) * inv3;
  float mx = fmaxf(m0, fmaxf(m1, m2));
  float e0 = __expf(m0 - mx), e1 = __expf(m1 - mx), e2 = __expf(m2 - mx);
  float inv = 1.f / (e0 + e1 + e2);
  float c0 = 3.f * inv * e0, c1 = 3.f * inv * e1, c2 = 3.f * inv * e2;

  float hh0 = __shfl_xor(h0, 32);
  float hh1 = __shfl_xor(h1, 32);
  float hh2 = __shfl_xor(h2, 32);
  float hh3 = __shfl_xor(h3, 32);

  if (!isHigh) {
    floatx4 o;
    o.x = c0 * h0 + c1 * hh0 + c2 * q0;
    o.y = c0 * h1 + c1 * hh1 + c2 * q1;
    o.z = c0 * h2 + c1 * hh2 + c2 * q2;
    o.w = c0 * h3 + c1 * hh3 + c2 * q3;
    __builtin_nontemporal_store(o,
                                (floatx4*)&out[(size_t)node * D_OUT + dbase]);
  }
}

// ---------------------------------------------------------------------------
extern "C" void kernel_launch(void* const* d_in, const int* in_sizes, int n_in,
                              void* d_out, int out_size, void* d_ws,
                              size_t ws_size, hipStream_t stream) {
  const float* x    = (const float*)d_in[0];
  const int*   esrc = (const int*)d_in[1];
  const int*   edst = (const int*)d_in[2];
  const float* wlo  = (const float*)d_in[3];
  const float* whi  = (const float*)d_in[4];
  const float* Wl   = (const float*)d_in[6];
  const float* Wh   = (const float*)d_in[7];
  const float* Wm   = (const float*)d_in[8];
  const float* alo  = (const float*)d_in[9];
  const float* ahi  = (const float*)d_in[10];
  const float* amlp = (const float*)d_in[11];
  const float* av   = (const float*)d_in[12];
  float* out = (float*)d_out;

  const int N = in_sizes[0] / D_IN;  // 100000
  const int E = in_sizes[1];         // 1600000
  const int NB1 = (N + 127) >> 7;    // coarse buckets (782)
  const int M = NB1 * NHB;           // bh entries (200192)

  char* ws = (char*)d_ws;
  size_t off = 0;
  auto carve = [&](size_t bytes) -> void* {
    void* p = ws + off;
    off = (off + bytes + 255) & ~(size_t)255;
    return p;
  };
  unsigned short* Zg     = (unsigned short*)carve((size_t)N * 256 * 2);
  unsigned short* Zm     = (unsigned short*)carve((size_t)N * 128 * 2);
  unsigned short* Bpack  = (unsigned short*)carve(98304 * 2);
  int*   bh     = (int*)carve((size_t)M * 4);
  int*   bhscan = (int*)carve((size_t)M * 4);
  int*   bsum   = (int*)carve(512 * 4);
  int*   rowptr = (int*)carve((size_t)(N + 1) * 4);
  int*   ticket = (int*)carve(256);
  uint2* tmp    = (uint2*)carve((size_t)E * 8);
  uint2* meta   = (uint2*)carve((size_t)E * 8);

  int nscan = (M + 2047) / 2048;  // 98

  // L1: hist + repack (+ ticket reset)
  hist_prep_kernel<<<NHB + 192, 512, 0, stream>>>(Wl, Wh, Wm, Bpack, edst, bh,
                                                  E, NB1, ticket);
  // L2: single-pass scan (scan1 + last-block scan2)
  scan_kernel<<<nscan, 512, 0, stream>>>(bh, bhscan, bsum, M, nscan, ticket);
  // L3: fused gemm (f32 A, in-staging cvt) + coarse scatter
  int ngemm = (N + 63) / 64;
  gemm_sort_kernel<<<ngemm + NHB, 512, 0, stream>>>(
      x, Bpack, Zg, Zm, N, esrc, edst, wlo, whi, bhscan, bsum, tmp, E, NB1);
  // L4: fine sort within buckets -> meta + rowptr
  fine_kernel<<<NB1, 512, 0, stream>>>(tmp, bhscan, bsum, meta, rowptr, NB1, N,
                                       E);
  // L5: node
  node_kernel<<<(N + 1) / 2, 128, 0, stream>>>(
      Zg, Zm, rowptr, (const unsigned long long*)meta, alo, ahi, amlp, av, out,
      N);
}